// Round 3
// baseline (288.270 us; speedup 1.0000x reference)
//
#include <hip/hip_runtime.h>
#include <hip/hip_bf16.h>
#include <math.h>

#define S_LEN 2048
#define D_DIM 1024
#define NHEAD 16

typedef __attribute__((ext_vector_type(8))) short bf16x8;
typedef __attribute__((ext_vector_type(4))) float floatx4;

__device__ __forceinline__ short f32_bf16(float f) {
  union { float f; unsigned u; } v; v.f = f;
  unsigned r = v.u + 0x7FFFu + ((v.u >> 16) & 1u);
  return (short)(r >> 16);
}

__device__ __forceinline__ float exp2_fast(float x) {
#if __has_builtin(__builtin_amdgcn_exp2f)
  return __builtin_amdgcn_exp2f(x);
#else
  float r; asm("v_exp_f32 %0, %1" : "=v"(r) : "v"(x)); return r;
#endif
}

__device__ __forceinline__ void gload16(const void* g, void* l) {
  __builtin_amdgcn_global_load_lds((const __attribute__((address_space(1))) unsigned*)g,
                                   (__attribute__((address_space(3))) unsigned*)l,
                                   16, 0, 0);
}

// ---------------- prep: RMSNorm (blocks 0..8191) + coalesced weight transpose
__global__ __launch_bounds__(256) void prep_k(const float* __restrict__ x,
                                              const float* __restrict__ lnw,
                                              const float* __restrict__ wq,
                                              const float* __restrict__ wk,
                                              const float* __restrict__ wv,
                                              const float* __restrict__ wo,
                                              short* __restrict__ xb,
                                              short* __restrict__ oqkv,
                                              short* __restrict__ owo) {
  if (blockIdx.x < 8192) {
    int row = blockIdx.x;
    const float4* xr = (const float4*)(x + (size_t)row * D_DIM);
    float4 v = xr[threadIdx.x];
    float ss = v.x*v.x + v.y*v.y + v.z*v.z + v.w*v.w;
    #pragma unroll
    for (int off = 32; off > 0; off >>= 1) ss += __shfl_xor(ss, off);
    __shared__ float red[4];
    if ((threadIdx.x & 63) == 0) red[threadIdx.x >> 6] = ss;
    __syncthreads();
    float scale = rsqrtf((red[0]+red[1]+red[2]+red[3]) * (1.f/D_DIM) + 1e-6f);
    float4 wv4 = ((const float4*)lnw)[threadIdx.x];
    short4 o;
    o.x = f32_bf16(v.x*scale*wv4.x);
    o.y = f32_bf16(v.y*scale*wv4.y);
    o.z = f32_bf16(v.z*scale*wv4.z);
    o.w = f32_bf16(v.w*scale*wv4.w);
    ((short4*)xb)[(size_t)row*256 + threadIdx.x] = o;
  } else {
    __shared__ float tile[64][65];
    int id = blockIdx.x - 8192;          // 0..1023
    int m  = id >> 8;                    // 0=wq 1=wk 2=wv 3=wo
    int tt = id & 255;
    int tn = tt >> 4, tk = tt & 15;      // 64x64 tile coords
    const float* src = (m == 0) ? wq : (m == 1) ? wk : (m == 2) ? wv : wo;
    float scale = (m == 0) ? 1.44269504f : 1.0f;
    int t = threadIdx.x;
    int kl  = t >> 4;                    // 0..15
    int nl4 = t & 15;                    // float4 index within row
    #pragma unroll
    for (int i = 0; i < 4; i++) {
      int k = i*16 + kl;
      float4 v = *(const float4*)&src[(size_t)(tk*64 + k)*1024 + tn*64 + nl4*4];
      tile[k][nl4*4+0] = v.x;
      tile[k][nl4*4+1] = v.y;
      tile[k][nl4*4+2] = v.z;
      tile[k][nl4*4+3] = v.w;
    }
    __syncthreads();
    short* dst = (m < 3) ? oqkv : owo;
    size_t nbase = (m < 3) ? (size_t)m * 1024 : 0;
    #pragma unroll
    for (int i = 0; i < 2; i++) {
      int idx = i*256 + t;               // 0..511
      int nl = idx >> 3;                 // 0..63
      int g  = idx & 7;                  // 8-wide k chunk
      short tmp[8];
      #pragma unroll
      for (int j = 0; j < 8; j++) tmp[j] = f32_bf16(tile[g*8 + j][nl] * scale);
      *(bf16x8*)&dst[(nbase + tn*64 + nl)*1024 + tk*64 + g*8] = *(bf16x8*)tmp;
    }
  }
}

// ---------------- GEMM 256x128, 8 waves, BK=32, ring-4 LDS, counted vmcnt ----
// K fixed at 1024 (32 steps). Uniform 3 global_load_lds per wave per K-tile
// (A: 2 granules of 16 rows, B: 1), so counted vmcnt is exact: steady-state
// stage t+3 during iter t, end-of-iter vmcnt(6) guarantees tile t+1 landed.
// Grid: QKV 768 blocks (32x24 tiles, 3 exact passes of 256 CUs), out-proj 256.
template<bool WRITE_VT, bool ADD_RES>
__global__ __launch_bounds__(512) void gemm256(const short* __restrict__ A,
                                               const short* __restrict__ Bt,
                                               short* __restrict__ Cb,
                                               float* __restrict__ Cf,
                                               const float* __restrict__ res,
                                               short* __restrict__ vt,
                                               int N, int NBN) {
  __shared__ __align__(16) short As[4][256*32];   // 64 KB
  __shared__ __align__(16) short Bs[4][128*32];   // 32 KB
  const int tid = threadIdx.x;
  const int w = tid >> 6, lane = tid & 63, quad = lane >> 4, l16 = lane & 15;
  const int wm = w >> 2, wn = w & 3;               // 2x4 wave grid
  const int id = blockIdx.x;
  const int o = (id & 7) * (gridDim.x >> 3) + (id >> 3);   // XCD-chunked
  const int bm = o / NBN, bn = o % NBN;
  const short* Ag = A  + (size_t)bm * 256 * 1024;
  const short* Bg = Bt + (size_t)bn * 128 * 1024;
  const int r4 = lane >> 2, c4 = lane & 3;
  const int lc  = c4 ^ ((r4 >> 1) & 3);            // staging chunk swizzle (2-way)
  const int swz = (quad ^ ((l16 >> 1) & 3)) * 8;   // fragment-read swizzle

  floatx4 acc[8][2] = {};

  #define SA(t_) do {                                                          \
    gload16(Ag + (size_t)((w    )*16 + r4) * 1024 + (t_)*32 + lc*8,            \
            &As[(t_) & 3][(w    )*512]);                                       \
    gload16(Ag + (size_t)((w + 8)*16 + r4) * 1024 + (t_)*32 + lc*8,            \
            &As[(t_) & 3][(w + 8)*512]);                                       \
  } while (0)
  #define SB(t_) do {                                                          \
    gload16(Bg + (size_t)((w    )*16 + r4) * 1024 + (t_)*32 + lc*8,            \
            &Bs[(t_) & 3][(w    )*512]);                                       \
  } while (0)

  #define PH(t_, STG_, VMW_) do {                                              \
    const short* Ab = &As[(t_) & 3][0];                                        \
    const short* Bb = &Bs[(t_) & 3][0];                                        \
    bf16x8 af[8], bf0, bf1;                                                    \
    _Pragma("unroll")                                                          \
    for (int i = 0; i < 8; i++)                                                \
      af[i] = *(const bf16x8*)&Ab[(wm*128 + i*16 + l16)*32 + swz];             \
    bf0 = *(const bf16x8*)&Bb[(wn*32 +  0 + l16)*32 + swz];                    \
    if (STG_) SA((t_) + 3);                                                    \
    asm volatile("s_waitcnt lgkmcnt(0)");                                      \
    __builtin_amdgcn_sched_barrier(0);                                         \
    __builtin_amdgcn_s_setprio(1);                                             \
    _Pragma("unroll")                                                          \
    for (int i = 0; i < 8; i++)                                                \
      acc[i][0] = __builtin_amdgcn_mfma_f32_16x16x32_bf16(af[i], bf0, acc[i][0], 0, 0, 0); \
    __builtin_amdgcn_s_setprio(0);                                             \
    bf1 = *(const bf16x8*)&Bb[(wn*32 + 16 + l16)*32 + swz];                    \
    if (STG_) SB((t_) + 3);                                                    \
    asm volatile("s_waitcnt lgkmcnt(0)");                                      \
    __builtin_amdgcn_sched_barrier(0);                                         \
    __builtin_amdgcn_s_setprio(1);                                             \
    _Pragma("unroll")                                                          \
    for (int i = 0; i < 8; i++)                                                \
      acc[i][1] = __builtin_amdgcn_mfma_f32_16x16x32_bf16(af[i], bf1, acc[i][1], 0, 0, 0); \
    __builtin_amdgcn_s_setprio(0);                                             \
    asm volatile("s_waitcnt " VMW_);                                           \
    __builtin_amdgcn_s_barrier();                                              \
    __builtin_amdgcn_sched_barrier(0);                                         \
  } while (0)

  // prologue: stage tiles 0,1,2 (9 loads/wave); drain tile 0 via vmcnt(6)
  SA(0); SB(0); SA(1); SB(1); SA(2); SB(2);
  asm volatile("s_waitcnt vmcnt(6)");
  __builtin_amdgcn_s_barrier();
  __builtin_amdgcn_sched_barrier(0);

  #pragma unroll 1
  for (int t = 0; t < 29; ++t) PH(t, true, "vmcnt(6)");
  PH(29, false, "vmcnt(3)");
  PH(30, false, "vmcnt(0)");
  PH(31, false, "vmcnt(0)");
  #undef SA
  #undef SB
  #undef PH

  if (WRITE_VT && bn >= 16) {
    // V columns: write transposed into vt[bh*64+hd][s]
    #pragma unroll
    for (int i = 0; i < 8; i++) {
      int row0 = bm*256 + wm*128 + i*16 + quad*4;
      int b = row0 >> 11, s = row0 & 2047;
      #pragma unroll
      for (int j = 0; j < 2; j++) {
        int hcol = (bn - 16)*128 + wn*32 + j*16 + l16;   // 0..1023
        short4 st;
        st.x = f32_bf16(acc[i][j][0]);
        st.y = f32_bf16(acc[i][j][1]);
        st.z = f32_bf16(acc[i][j][2]);
        st.w = f32_bf16(acc[i][j][3]);
        int bh = (b << 4) + (hcol >> 6);
        *(short4*)&vt[((size_t)(bh*64 + (hcol & 63)))*2048 + s] = st;
      }
    }
    return;
  }

  #pragma unroll
  for (int i = 0; i < 8; i++) {
    int row0 = bm*256 + wm*128 + i*16 + quad*4;
    #pragma unroll
    for (int j = 0; j < 2; j++) {
      int col = bn*128 + wn*32 + j*16 + l16;
      #pragma unroll
      for (int r = 0; r < 4; r++) {
        size_t idx = (size_t)(row0 + r) * N + col;
        if (ADD_RES) Cf[idx] = res[idx] + acc[i][j][r];
        else         Cb[idx] = f32_bf16(acc[i][j][r]);
      }
    }
  }
}

// ---------------- Flash attention v7: T15 deferred-PV pipeline.
// PV of tile t-1 (MFMA, uses pfP) is scheduled in the same region as
// exp/pack of tile t (VALU) -- independent, so the compiler interleaves the
// two pipes within a wave. V is ring-3 in LDS (K stays ring-2); iter 0's PV
// is a branchless no-op (pfP=0, Vb[2] zeroed).
__global__ __launch_bounds__(512) void flash_k(const short* __restrict__ qkv,
                                               const short* __restrict__ vt,
                                               const float* __restrict__ rel_emb,
                                               short* __restrict__ ctx) {
  __shared__ __align__(16) short Kb[2][64*64];   // rows = permuted keys, cols = d
  __shared__ __align__(16) short Vb[3][64*64];   // rows = hd, cols = keys
  __shared__ float lut2[132];                    // bias * log2(e)

  const int L = blockIdx.x + 8*blockIdx.y;   // grid (8,64) = 512 blocks
  const int xcd = L & 7, kk_ = L >> 3;
  const int bh = xcd*8 + (kk_ >> 3);
  const int qt = kk_ & 7;
  const int b = bh >> 4, h = bh & 15;
  const int t = threadIdx.x, w = t >> 6, lane = t & 63, quad = lane >> 4, l16 = lane & 15;
  const float L2E = 1.44269504f;

  if (t < 129) {
    int rp = t, bucket;
    if (rp < 16) bucket = rp;
    else {
      bucket = 16 + (int)(logf((float)rp * 0.0625f) * (16.f / logf(8.f)));
      if (bucket > 31) bucket = 31;
    }
    lut2[t] = rel_emb[bucket*16 + h] * L2E;
  }
  const float bfut  = rel_emb[h] * L2E;            // d <= 0  -> bucket 0
  const float bpast = rel_emb[31*16 + h] * L2E;    // d >= 128 -> bucket 31
  const floatx4 bf4 = {bfut, bfut, bfut, bfut};
  const floatx4 bp4 = {bpast, bpast, bpast, bpast};
  const floatx4 zz4 = {0.f, 0.f, 0.f, 0.f};

  const int srow = lane >> 3;          // 0..7
  const int slc  = (lane & 7) ^ srow;  // XOR chunk swizzle
  const int rho  = w*8 + srow;
  const int kperm = 32*(rho >> 5) + 8*((rho >> 2) & 3) + 4*((rho >> 4) & 1) + (rho & 3);

  const short* kgU = qkv + ((size_t)b*S_LEN)*3072 + 1024 + h*64;  // wave-uniform
  const int    loK = kperm*3072 + slc*8;                           // lane-const
  const short* vgU = vt + ((size_t)bh*64)*2048;
  const int    loV = rho*2048 + slc*8;

  // zero Vb[2] (read by iter 0's no-op PV)
  {
    bf16x8 z = {};
    *(bf16x8*)&Vb[2][t*8] = z;
  }

  bf16x8 qB[2][2];
  #pragma unroll
  for (int rb = 0; rb < 2; rb++) {
    const short* qb = qkv + ((size_t)(b*S_LEN + qt*256 + rb*128 + w*16 + l16))*3072 + h*64;
    qB[rb][0] = *(const bf16x8*)&qb[quad*8];
    qB[rb][1] = *(const bf16x8*)&qb[32 + quad*8];
  }

  floatx4 o[2][4] = {};      // O^T accumulators: row=d(quad*4+r), col=query(l16)
  floatx4 li4[2] = {};       // row sums per query
  const short ONE = (short)0x3F80;
  bf16x8 onesA = {ONE, ONE, ONE, ONE, ONE, ONE, ONE, ONE};
  bf16x8 pfP[2][2] = {};     // previous tile's packed P (zero -> first PV no-op)

  const int swz0 = (quad     ^ (l16 & 7)) * 8;
  const int swz1 = ((quad+4) ^ (l16 & 7)) * 8;

  int vnext = 1;   // (kt+1)%3
  int vprev = 2;   // (kt-1)%3

  #define STAGE_T(KP_, VN_, KT_) do {                                           \
    const short* ka_ = kgU + (size_t)(KT_)*196608 + loK;                        \
    gload16(ka_, &Kb[KP_][(w*8)*64]);                                           \
    const short* va_ = vgU + loV + (KT_)*64;                                    \
    gload16(va_, &Vb[VN_][(w*8)*64]);                                           \
  } while (0)

  #define BODY(P_, KT_) do {                                                    \
    __syncthreads();                                                            \
    if ((KT_) < 31) STAGE_T((P_) ^ 1, vnext, (KT_) + 1);                        \
    bool boundary = ((KT_) >= 4*qt - 2) && ((KT_) <= 4*qt + 3);                 \
    floatx4 cinit = boundary ? zz4 : (((KT_) >= 4*qt) ? bf4 : bp4);             \
    floatx4 sc[2][4];                                                           \
    _Pragma("unroll")                                                           \
    for (int c = 0; c < 4; c++) {                                               \
      int rowA = (c*16 + l16)*64;                                               \
      bf16x8 ka0 = *(const bf16x8*)&Kb[P_][rowA + swz0];                        \
      bf16x8 ka1 = *(const bf16x8*)&Kb[P_][rowA + swz1];                        \
      _Pragma("unroll")                                                         \
      for (int rb = 0; rb < 2; rb++) {                                          \
        floatx4 z = __builtin_amdgcn_mfma_f32_16x16x32_bf16(ka0, qB[rb][0], cinit, 0, 0, 0); \
        z = __builtin_amdgcn_mfma_f32_16x16x32_bf16(ka1, qB[rb][1], z, 0, 0, 0);\
        sc[rb][c] = z;                                                          \
      }                                                                         \
    }                                                                           \
    if (boundary) {                                                             \
      _Pragma("unroll")                                                         \
      for (int rb = 0; rb < 2; rb++) {                                          \
        int q0 = qt*256 + rb*128 + w*16 + l16;                                  \
        _Pragma("unroll")                                                       \
        for (int c = 0; c < 4; c++) {                                           \
          int kk = (KT_)*64 + 32*(c >> 1) + 8*quad + 4*(c & 1);                 \
          _Pragma("unroll")                                                     \
          for (int r = 0; r < 4; r++) {                                         \
            int d = q0 - (kk + r);                                              \
            d = d < 0 ? 0 : (d > 128 ? 128 : d);                                \
            sc[rb][c][r] += lut2[d];                                            \
          }                                                                     \
        }                                                                       \
      }                                                                         \
    }                                                                           \
    _Pragma("unroll")                                                           \
    for (int rb = 0; rb < 2; rb++)                                              \
      _Pragma("unroll")                                                         \
      for (int c = 0; c < 4; c++)                                               \
        _Pragma("unroll")                                                       \
        for (int r = 0; r < 4; r++)                                             \
          sc[rb][c][r] = exp2_fast(sc[rb][c][r]);                               \
    bf16x8 pfL[2][2];                                                           \
    _Pragma("unroll")                                                           \
    for (int rb = 0; rb < 2; rb++) {                                            \
      _Pragma("unroll")                                                         \
      for (int hh = 0; hh < 2; hh++) {                                          \
        union { bf16x8 v; unsigned u[4]; } pk;                                  \
        floatx4 a = sc[rb][2*hh], bb = sc[rb][2*hh + 1];                        \
        pk.u[0] = __builtin_amdgcn_perm(__float_as_uint(a[1]),  __float_as_uint(a[0]),  0x07060302); \
        pk.u[1] = __builtin_amdgcn_perm(__float_as_uint(a[3]),  __float_as_uint(a[2]),  0x07060302); \
        pk.u[2] = __builtin_amdgcn_perm(__float_as_uint(bb[1]), __float_as_uint(bb[0]), 0x07060302); \
        pk.u[3] = __builtin_amdgcn_perm(__float_as_uint(bb[3]), __float_as_uint(bb[2]), 0x07060302); \
        pfL[rb][hh] = pk.v;                                                     \
      }                                                                         \
    }                                                                           \
    /* deferred PV: tile KT_-1, independent of sc/exp/pack above */             \
    _Pragma("unroll")                                                           \
    for (int jj = 0; jj < 4; jj++) {                                            \
      int rowV = (jj*16 + l16)*64;                                              \
      bf16x8 va0 = *(const bf16x8*)&Vb[vprev][rowV + swz0];                     \
      bf16x8 va1 = *(const bf16x8*)&Vb[vprev][rowV + swz1];                     \
      _Pragma("unroll")                                                         \
      for (int rb = 0; rb < 2; rb++) {                                          \
        o[rb][jj] = __builtin_amdgcn_mfma_f32_16x16x32_bf16(va0, pfP[rb][0], o[rb][jj], 0, 0, 0); \
        o[rb][jj] = __builtin_amdgcn_mfma_f32_16x16x32_bf16(va1, pfP[rb][1], o[rb][jj], 0, 0, 0); \
      }                                                                         \
    }                                                                           \
    _Pragma("unroll")                                                           \
    for (int rb = 0; rb < 2; rb++) {                                            \
      li4[rb] = __builtin_amdgcn_mfma_f32_16x16x32_bf16(onesA, pfL[rb][0], li4[rb], 0, 0, 0); \
      li4[rb] = __builtin_amdgcn_mfma_f32_16x16x32_bf16(onesA, pfL[rb][1], li4[rb], 0, 0, 0); \
    }                                                                           \
    _Pragma("unroll")                                                           \
    for (int rb = 0; rb < 2; rb++) {                                            \
      pfP[rb][0] = pfL[rb][0];                                                  \
      pfP[rb][1] = pfL[rb][1];                                                  \
    }                                                                           \
    vprev = (vprev == 2) ? 0 : vprev + 1;                                       \
    vnext = (vnext == 2) ? 0 : vnext + 1;                                       \
  } while (0)

  STAGE_T(0, 0, 0);   // tile 0: K->Kb[0], V->Vb[0]
  for (int kt = 0; kt < 32; kt += 2) {
    BODY(0, kt);
    BODY(1, kt + 1);
  }

  // final PV: tile 31 (pfP), Vb[vprev] (=Vb[1]); data landed before iter 31's sync
  #pragma unroll
  for (int jj = 0; jj < 4; jj++) {
    int rowV = (jj*16 + l16)*64;
    bf16x8 va0 = *(const bf16x8*)&Vb[vprev][rowV + swz0];
    bf16x8 va1 = *(const bf16x8*)&Vb[vprev][rowV + swz1];
    #pragma unroll
    for (int rb = 0; rb < 2; rb++) {
      o[rb][jj] = __builtin_amdgcn_mfma_f32_16x16x32_bf16(va0, pfP[rb][0], o[rb][jj], 0, 0, 0);
      o[rb][jj] = __builtin_amdgcn_mfma_f32_16x16x32_bf16(va1, pfP[rb][1], o[rb][jj], 0, 0, 0);
    }
  }

  // ---- epilogue: normalize (per-query sum is lane-local) and store ----
  #pragma unroll
  for (int rb = 0; rb < 2; rb++) {
    float inv = 1.f / li4[rb][0];
    size_t row = (size_t)(b*S_LEN + qt*256 + rb*128 + w*16 + l16);
    #pragma unroll
    for (int jj = 0; jj < 4; jj++) {
      short4 st;
      st.x = f32_bf16(o[rb][jj][0] * inv);
      st.y = f32_bf16(o[rb][jj][1] * inv);
      st.z = f32_bf16(o[rb][jj][2] * inv);
      st.w = f32_bf16(o[rb][jj][3] * inv);
      *(short4*)&ctx[row*1024 + h*64 + jj*16 + quad*4] = st;
    }
  }
  #undef STAGE_T
  #undef BODY
}

extern "C" void kernel_launch(void* const* d_in, const int* in_sizes, int n_in,
                              void* d_out, int out_size, void* d_ws, size_t ws_size,
                              hipStream_t stream) {
  const float* input_ids = (const float*)d_in[0];
  const float* wq      = (const float*)d_in[2];
  const float* wk      = (const float*)d_in[3];
  const float* wv      = (const float*)d_in[4];
  const float* wo      = (const float*)d_in[5];
  const float* rel_emb = (const float*)d_in[6];
  const float* ln_w    = (const float*)d_in[7];
  float* out = (float*)d_out;

  char* ws = (char*)d_ws;
  short* xb     = (short*)ws;  ws += (size_t)8192*1024*2;   // 16 MB
  short* wqkv_t = (short*)ws;  ws += (size_t)3072*1024*2;   // 6 MB
  short* wo_t   = (short*)ws;  ws += (size_t)1024*1024*2;   // 2 MB
  short* qkv    = (short*)ws;  ws += (size_t)8192*3072*2;   // 50 MB
  short* vt     = (short*)ws;  ws += (size_t)64*64*2048*2;  // 16 MB
  short* ctx    = (short*)ws;  ws += (size_t)8192*1024*2;   // 16 MB

  prep_k<<<8192 + 1024, 256, 0, stream>>>(input_ids, ln_w, wq, wk, wv, wo,
                                          xb, wqkv_t, wo_t);
  gemm256<true, false><<<768, 512, 0, stream>>>(xb, wqkv_t, qkv, nullptr,
                                                nullptr, vt, 3072, 24);
  flash_k<<<dim3(8, 64), 512, 0, stream>>>(qkv, vt, rel_emb, ctx);
  gemm256<false, true><<<256, 512, 0, stream>>>(ctx, wo_t, nullptr, out,
                                                input_ids, nullptr, 1024, 8);
}

// Round 4
// 269.057 us; speedup vs baseline: 1.0714x; 1.0714x over previous
//
#include <hip/hip_runtime.h>
#include <hip/hip_bf16.h>
#include <math.h>

#define S_LEN 2048
#define D_DIM 1024
#define NHEAD 16

typedef __attribute__((ext_vector_type(8))) short bf16x8;
typedef __attribute__((ext_vector_type(4))) float floatx4;

__device__ __forceinline__ short f32_bf16(float f) {
  union { float f; unsigned u; } v; v.f = f;
  unsigned r = v.u + 0x7FFFu + ((v.u >> 16) & 1u);
  return (short)(r >> 16);
}

__device__ __forceinline__ float exp2_fast(float x) {
#if __has_builtin(__builtin_amdgcn_exp2f)
  return __builtin_amdgcn_exp2f(x);
#else
  float r; asm("v_exp_f32 %0, %1" : "=v"(r) : "v"(x)); return r;
#endif
}

__device__ __forceinline__ void gload16(const void* g, void* l) {
  __builtin_amdgcn_global_load_lds((const __attribute__((address_space(1))) unsigned*)g,
                                   (__attribute__((address_space(3))) unsigned*)l,
                                   16, 0, 0);
}

// ---------------- prep: RMSNorm (blocks 0..8191) + coalesced weight transpose
__global__ __launch_bounds__(256) void prep_k(const float* __restrict__ x,
                                              const float* __restrict__ lnw,
                                              const float* __restrict__ wq,
                                              const float* __restrict__ wk,
                                              const float* __restrict__ wv,
                                              const float* __restrict__ wo,
                                              short* __restrict__ xb,
                                              short* __restrict__ oqkv,
                                              short* __restrict__ owo) {
  if (blockIdx.x < 8192) {
    int row = blockIdx.x;
    const float4* xr = (const float4*)(x + (size_t)row * D_DIM);
    float4 v = xr[threadIdx.x];
    float ss = v.x*v.x + v.y*v.y + v.z*v.z + v.w*v.w;
    #pragma unroll
    for (int off = 32; off > 0; off >>= 1) ss += __shfl_xor(ss, off);
    __shared__ float red[4];
    if ((threadIdx.x & 63) == 0) red[threadIdx.x >> 6] = ss;
    __syncthreads();
    float scale = rsqrtf((red[0]+red[1]+red[2]+red[3]) * (1.f/D_DIM) + 1e-6f);
    float4 wv4 = ((const float4*)lnw)[threadIdx.x];
    short4 o;
    o.x = f32_bf16(v.x*scale*wv4.x);
    o.y = f32_bf16(v.y*scale*wv4.y);
    o.z = f32_bf16(v.z*scale*wv4.z);
    o.w = f32_bf16(v.w*scale*wv4.w);
    ((short4*)xb)[(size_t)row*256 + threadIdx.x] = o;
  } else {
    __shared__ float tile[64][65];
    int id = blockIdx.x - 8192;          // 0..1023
    int m  = id >> 8;                    // 0=wq 1=wk 2=wv 3=wo
    int tt = id & 255;
    int tn = tt >> 4, tk = tt & 15;      // 64x64 tile coords
    const float* src = (m == 0) ? wq : (m == 1) ? wk : (m == 2) ? wv : wo;
    float scale = (m == 0) ? 1.44269504f : 1.0f;
    int t = threadIdx.x;
    int kl  = t >> 4;                    // 0..15
    int nl4 = t & 15;                    // float4 index within row
    #pragma unroll
    for (int i = 0; i < 4; i++) {
      int k = i*16 + kl;
      float4 v = *(const float4*)&src[(size_t)(tk*64 + k)*1024 + tn*64 + nl4*4];
      tile[k][nl4*4+0] = v.x;
      tile[k][nl4*4+1] = v.y;
      tile[k][nl4*4+2] = v.z;
      tile[k][nl4*4+3] = v.w;
    }
    __syncthreads();
    short* dst = (m < 3) ? oqkv : owo;
    size_t nbase = (m < 3) ? (size_t)m * 1024 : 0;
    #pragma unroll
    for (int i = 0; i < 2; i++) {
      int idx = i*256 + t;               // 0..511
      int nl = idx >> 3;                 // 0..63
      int g  = idx & 7;                  // 8-wide k chunk
      short tmp[8];
      #pragma unroll
      for (int j = 0; j < 8; j++) tmp[j] = f32_bf16(tile[g*8 + j][nl] * scale);
      *(bf16x8*)&dst[(nbase + tn*64 + nl)*1024 + tk*64 + g*8] = *(bf16x8*)tmp;
    }
  }
}

// ---------------- GEMM 256x128, 8 waves, BK=32, ring-4 LDS, counted vmcnt ----
// K fixed at 1024 (32 steps). Uniform 3 global_load_lds per wave per K-tile
// (A: 2 granules of 16 rows, B: 1), so counted vmcnt is exact: steady-state
// stage t+3 during iter t, end-of-iter vmcnt(6) guarantees tile t+1 landed.
// Grid: QKV 768 blocks (32x24 tiles, 3 exact passes of 256 CUs), out-proj 256.
template<bool WRITE_VT, bool ADD_RES>
__global__ __launch_bounds__(512) void gemm256(const short* __restrict__ A,
                                               const short* __restrict__ Bt,
                                               short* __restrict__ Cb,
                                               float* __restrict__ Cf,
                                               const float* __restrict__ res,
                                               short* __restrict__ vt,
                                               int N, int NBN) {
  __shared__ __align__(16) short As[4][256*32];   // 64 KB
  __shared__ __align__(16) short Bs[4][128*32];   // 32 KB
  const int tid = threadIdx.x;
  const int w = tid >> 6, lane = tid & 63, quad = lane >> 4, l16 = lane & 15;
  const int wm = w >> 2, wn = w & 3;               // 2x4 wave grid
  const int id = blockIdx.x;
  const int o = (id & 7) * (gridDim.x >> 3) + (id >> 3);   // XCD-chunked
  const int bm = o / NBN, bn = o % NBN;
  const short* Ag = A  + (size_t)bm * 256 * 1024;
  const short* Bg = Bt + (size_t)bn * 128 * 1024;
  const int r4 = lane >> 2, c4 = lane & 3;
  const int lc  = c4 ^ ((r4 >> 1) & 3);            // staging chunk swizzle (2-way)
  const int swz = (quad ^ ((l16 >> 1) & 3)) * 8;   // fragment-read swizzle

  floatx4 acc[8][2] = {};

  #define SA(t_) do {                                                          \
    gload16(Ag + (size_t)((w    )*16 + r4) * 1024 + (t_)*32 + lc*8,            \
            &As[(t_) & 3][(w    )*512]);                                       \
    gload16(Ag + (size_t)((w + 8)*16 + r4) * 1024 + (t_)*32 + lc*8,            \
            &As[(t_) & 3][(w + 8)*512]);                                       \
  } while (0)
  #define SB(t_) do {                                                          \
    gload16(Bg + (size_t)((w    )*16 + r4) * 1024 + (t_)*32 + lc*8,            \
            &Bs[(t_) & 3][(w    )*512]);                                       \
  } while (0)

  #define PH(t_, STG_, VMW_) do {                                              \
    const short* Ab = &As[(t_) & 3][0];                                        \
    const short* Bb = &Bs[(t_) & 3][0];                                        \
    bf16x8 af[8], bf0, bf1;                                                    \
    _Pragma("unroll")                                                          \
    for (int i = 0; i < 8; i++)                                                \
      af[i] = *(const bf16x8*)&Ab[(wm*128 + i*16 + l16)*32 + swz];             \
    bf0 = *(const bf16x8*)&Bb[(wn*32 +  0 + l16)*32 + swz];                    \
    if (STG_) SA((t_) + 3);                                                    \
    asm volatile("s_waitcnt lgkmcnt(0)");                                      \
    __builtin_amdgcn_sched_barrier(0);                                         \
    __builtin_amdgcn_s_setprio(1);                                             \
    _Pragma("unroll")                                                          \
    for (int i = 0; i < 8; i++)                                                \
      acc[i][0] = __builtin_amdgcn_mfma_f32_16x16x32_bf16(af[i], bf0, acc[i][0], 0, 0, 0); \
    __builtin_amdgcn_s_setprio(0);                                             \
    bf1 = *(const bf16x8*)&Bb[(wn*32 + 16 + l16)*32 + swz];                    \
    if (STG_) SB((t_) + 3);                                                    \
    asm volatile("s_waitcnt lgkmcnt(0)");                                      \
    __builtin_amdgcn_sched_barrier(0);                                         \
    __builtin_amdgcn_s_setprio(1);                                             \
    _Pragma("unroll")                                                          \
    for (int i = 0; i < 8; i++)                                                \
      acc[i][1] = __builtin_amdgcn_mfma_f32_16x16x32_bf16(af[i], bf1, acc[i][1], 0, 0, 0); \
    __builtin_amdgcn_s_setprio(0);                                             \
    asm volatile("s_waitcnt " VMW_);                                           \
    __builtin_amdgcn_s_barrier();                                              \
    __builtin_amdgcn_sched_barrier(0);                                         \
  } while (0)

  // prologue: stage tiles 0,1,2 (9 loads/wave); drain tile 0 via vmcnt(6)
  SA(0); SB(0); SA(1); SB(1); SA(2); SB(2);
  asm volatile("s_waitcnt vmcnt(6)");
  __builtin_amdgcn_s_barrier();
  __builtin_amdgcn_sched_barrier(0);

  #pragma unroll 1
  for (int t = 0; t < 29; ++t) PH(t, true, "vmcnt(6)");
  PH(29, false, "vmcnt(3)");
  PH(30, false, "vmcnt(0)");
  PH(31, false, "vmcnt(0)");
  #undef SA
  #undef SB
  #undef PH

  if (WRITE_VT && bn >= 16) {
    // V columns: write transposed into vt[bh*64+hd][s]
    #pragma unroll
    for (int i = 0; i < 8; i++) {
      int row0 = bm*256 + wm*128 + i*16 + quad*4;
      int b = row0 >> 11, s = row0 & 2047;
      #pragma unroll
      for (int j = 0; j < 2; j++) {
        int hcol = (bn - 16)*128 + wn*32 + j*16 + l16;   // 0..1023
        short4 st;
        st.x = f32_bf16(acc[i][j][0]);
        st.y = f32_bf16(acc[i][j][1]);
        st.z = f32_bf16(acc[i][j][2]);
        st.w = f32_bf16(acc[i][j][3]);
        int bh = (b << 4) + (hcol >> 6);
        *(short4*)&vt[((size_t)(bh*64 + (hcol & 63)))*2048 + s] = st;
      }
    }
    return;
  }

  #pragma unroll
  for (int i = 0; i < 8; i++) {
    int row0 = bm*256 + wm*128 + i*16 + quad*4;
    #pragma unroll
    for (int j = 0; j < 2; j++) {
      int col = bn*128 + wn*32 + j*16 + l16;
      #pragma unroll
      for (int r = 0; r < 4; r++) {
        size_t idx = (size_t)(row0 + r) * N + col;
        if (ADD_RES) Cf[idx] = res[idx] + acc[i][j][r];
        else         Cb[idx] = f32_bf16(acc[i][j][r]);
      }
    }
  }
}

// ---------------- Flash attention v6 (reverted from v7: deferred-PV cost
// occupancy via ring-3 LDS + VGPR growth and regressed 79.5 -> 95.9 us;
// cross-block wave overlap at 2 blocks/CU already covers MFMA||VALU).
__global__ __launch_bounds__(512) void flash_k(const short* __restrict__ qkv,
                                               const short* __restrict__ vt,
                                               const float* __restrict__ rel_emb,
                                               short* __restrict__ ctx) {
  __shared__ __align__(16) short Kb[2][64*64];
  __shared__ __align__(16) short Vb[2][64*64];
  __shared__ float lut2[132];

  const int L = blockIdx.x + 8*blockIdx.y;
  const int xcd = L & 7, kk_ = L >> 3;
  const int bh = xcd*8 + (kk_ >> 3);
  const int qt = kk_ & 7;
  const int b = bh >> 4, h = bh & 15;
  const int t = threadIdx.x, w = t >> 6, lane = t & 63, quad = lane >> 4, l16 = lane & 15;
  const float L2E = 1.44269504f;

  if (t < 129) {
    int rp = t, bucket;
    if (rp < 16) bucket = rp;
    else {
      bucket = 16 + (int)(logf((float)rp * 0.0625f) * (16.f / logf(8.f)));
      if (bucket > 31) bucket = 31;
    }
    lut2[t] = rel_emb[bucket*16 + h] * L2E;
  }
  const float bfut  = rel_emb[h] * L2E;
  const float bpast = rel_emb[31*16 + h] * L2E;
  const floatx4 bf4 = {bfut, bfut, bfut, bfut};
  const floatx4 bp4 = {bpast, bpast, bpast, bpast};
  const floatx4 zz4 = {0.f, 0.f, 0.f, 0.f};

  const int srow = lane >> 3;
  const int slc  = (lane & 7) ^ srow;
  const int rho  = w*8 + srow;
  const int kperm = 32*(rho >> 5) + 8*((rho >> 2) & 3) + 4*((rho >> 4) & 1) + (rho & 3);

  const short* kgU = qkv + ((size_t)b*S_LEN)*3072 + 1024 + h*64;
  const int    loK = kperm*3072 + slc*8;
  const short* vgU = vt + ((size_t)bh*64)*2048;
  const int    loV = rho*2048 + slc*8;

  bf16x8 qB[2][2];
  #pragma unroll
  for (int rb = 0; rb < 2; rb++) {
    const short* qb = qkv + ((size_t)(b*S_LEN + qt*256 + rb*128 + w*16 + l16))*3072 + h*64;
    qB[rb][0] = *(const bf16x8*)&qb[quad*8];
    qB[rb][1] = *(const bf16x8*)&qb[32 + quad*8];
  }

  floatx4 o[2][4] = {};
  floatx4 li4[2] = {};
  const short ONE = (short)0x3F80;
  bf16x8 onesA = {ONE, ONE, ONE, ONE, ONE, ONE, ONE, ONE};

  const int swz0 = (quad     ^ (l16 & 7)) * 8;
  const int swz1 = ((quad+4) ^ (l16 & 7)) * 8;

  #define STAGE(P_, KT_) do {                                                   \
    const short* ka_ = kgU + (size_t)(KT_)*196608 + loK;                        \
    gload16(ka_, &Kb[P_][(w*8)*64]);                                            \
    const short* va_ = vgU + loV + (KT_)*64;                                    \
    gload16(va_, &Vb[P_][(w*8)*64]);                                            \
  } while (0)

  #define BODY(P_, KT_) do {                                                    \
    __syncthreads();                                                            \
    if ((KT_) < 31) STAGE((P_) ^ 1, (KT_) + 1);                                 \
    bool boundary = ((KT_) >= 4*qt - 2) && ((KT_) <= 4*qt + 3);                 \
    floatx4 cinit = boundary ? zz4 : (((KT_) >= 4*qt) ? bf4 : bp4);             \
    floatx4 sc[2][4];                                                           \
    _Pragma("unroll")                                                           \
    for (int c = 0; c < 4; c++) {                                               \
      int rowA = (c*16 + l16)*64;                                               \
      bf16x8 ka0 = *(const bf16x8*)&Kb[P_][rowA + swz0];                        \
      bf16x8 ka1 = *(const bf16x8*)&Kb[P_][rowA + swz1];                        \
      _Pragma("unroll")                                                         \
      for (int rb = 0; rb < 2; rb++) {                                          \
        floatx4 z = __builtin_amdgcn_mfma_f32_16x16x32_bf16(ka0, qB[rb][0], cinit, 0, 0, 0); \
        z = __builtin_amdgcn_mfma_f32_16x16x32_bf16(ka1, qB[rb][1], z, 0, 0, 0);\
        sc[rb][c] = z;                                                          \
      }                                                                         \
    }                                                                           \
    if (boundary) {                                                             \
      _Pragma("unroll")                                                         \
      for (int rb = 0; rb < 2; rb++) {                                          \
        int q0 = qt*256 + rb*128 + w*16 + l16;                                  \
        _Pragma("unroll")                                                       \
        for (int c = 0; c < 4; c++) {                                           \
          int kk = (KT_)*64 + 32*(c >> 1) + 8*quad + 4*(c & 1);                 \
          _Pragma("unroll")                                                     \
          for (int r = 0; r < 4; r++) {                                         \
            int d = q0 - (kk + r);                                              \
            d = d < 0 ? 0 : (d > 128 ? 128 : d);                                \
            sc[rb][c][r] += lut2[d];                                            \
          }                                                                     \
        }                                                                       \
      }                                                                         \
    }                                                                           \
    _Pragma("unroll")                                                           \
    for (int rb = 0; rb < 2; rb++)                                              \
      _Pragma("unroll")                                                         \
      for (int c = 0; c < 4; c++)                                               \
        _Pragma("unroll")                                                       \
        for (int r = 0; r < 4; r++)                                             \
          sc[rb][c][r] = exp2_fast(sc[rb][c][r]);                               \
    bf16x8 pf[2][2];                                                            \
    _Pragma("unroll")                                                           \
    for (int rb = 0; rb < 2; rb++) {                                            \
      _Pragma("unroll")                                                         \
      for (int hh = 0; hh < 2; hh++) {                                          \
        union { bf16x8 v; unsigned u[4]; } pk;                                  \
        floatx4 a = sc[rb][2*hh], bb = sc[rb][2*hh + 1];                        \
        pk.u[0] = __builtin_amdgcn_perm(__float_as_uint(a[1]),  __float_as_uint(a[0]),  0x07060302); \
        pk.u[1] = __builtin_amdgcn_perm(__float_as_uint(a[3]),  __float_as_uint(a[2]),  0x07060302); \
        pk.u[2] = __builtin_amdgcn_perm(__float_as_uint(bb[1]), __float_as_uint(bb[0]), 0x07060302); \
        pk.u[3] = __builtin_amdgcn_perm(__float_as_uint(bb[3]), __float_as_uint(bb[2]), 0x07060302); \
        pf[rb][hh] = pk.v;                                                      \
      }                                                                         \
    }                                                                           \
    _Pragma("unroll")                                                           \
    for (int rb = 0; rb < 2; rb++) {                                            \
      li4[rb] = __builtin_amdgcn_mfma_f32_16x16x32_bf16(onesA, pf[rb][0], li4[rb], 0, 0, 0); \
      li4[rb] = __builtin_amdgcn_mfma_f32_16x16x32_bf16(onesA, pf[rb][1], li4[rb], 0, 0, 0); \
    }                                                                           \
    _Pragma("unroll")                                                           \
    for (int jj = 0; jj < 4; jj++) {                                            \
      int rowV = (jj*16 + l16)*64;                                              \
      bf16x8 va0 = *(const bf16x8*)&Vb[P_][rowV + swz0];                        \
      bf16x8 va1 = *(const bf16x8*)&Vb[P_][rowV + swz1];                        \
      _Pragma("unroll")                                                         \
      for (int rb = 0; rb < 2; rb++) {                                          \
        o[rb][jj] = __builtin_amdgcn_mfma_f32_16x16x32_bf16(va0, pf[rb][0], o[rb][jj], 0, 0, 0); \
        o[rb][jj] = __builtin_amdgcn_mfma_f32_16x16x32_bf16(va1, pf[rb][1], o[rb][jj], 0, 0, 0); \
      }                                                                         \
    }                                                                           \
  } while (0)

  STAGE(0, 0);
  for (int kt = 0; kt < 32; kt += 2) {
    BODY(0, kt);
    BODY(1, kt + 1);
  }

  #pragma unroll
  for (int rb = 0; rb < 2; rb++) {
    float inv = 1.f / li4[rb][0];
    size_t row = (size_t)(b*S_LEN + qt*256 + rb*128 + w*16 + l16);
    #pragma unroll
    for (int jj = 0; jj < 4; jj++) {
      short4 st;
      st.x = f32_bf16(o[rb][jj][0] * inv);
      st.y = f32_bf16(o[rb][jj][1] * inv);
      st.z = f32_bf16(o[rb][jj][2] * inv);
      st.w = f32_bf16(o[rb][jj][3] * inv);
      *(short4*)&ctx[row*1024 + h*64 + jj*16 + quad*4] = st;
    }
  }
  #undef STAGE
  #undef BODY
}

extern "C" void kernel_launch(void* const* d_in, const int* in_sizes, int n_in,
                              void* d_out, int out_size, void* d_ws, size_t ws_size,
                              hipStream_t stream) {
  const float* input_ids = (const float*)d_in[0];
  const float* wq      = (const float*)d_in[2];
  const float* wk      = (const float*)d_in[3];
  const float* wv      = (const float*)d_in[4];
  const float* wo      = (const float*)d_in[5];
  const float* rel_emb = (const float*)d_in[6];
  const float* ln_w    = (const float*)d_in[7];
  float* out = (float*)d_out;

  char* ws = (char*)d_ws;
  short* xb     = (short*)ws;  ws += (size_t)8192*1024*2;   // 16 MB
  short* wqkv_t = (short*)ws;  ws += (size_t)3072*1024*2;   // 6 MB
  short* wo_t   = (short*)ws;  ws += (size_t)1024*1024*2;   // 2 MB
  short* qkv    = (short*)ws;  ws += (size_t)8192*3072*2;   // 50 MB
  short* vt     = (short*)ws;  ws += (size_t)64*64*2048*2;  // 16 MB
  short* ctx    = (short*)ws;  ws += (size_t)8192*1024*2;   // 16 MB

  prep_k<<<8192 + 1024, 256, 0, stream>>>(input_ids, ln_w, wq, wk, wv, wo,
                                          xb, wqkv_t, wo_t);
  gemm256<true, false><<<768, 512, 0, stream>>>(xb, wqkv_t, qkv, nullptr,
                                                nullptr, vt, 3072, 24);
  flash_k<<<dim3(8, 64), 512, 0, stream>>>(qkv, vt, rel_emb, ctx);
  gemm256<false, true><<<256, 512, 0, stream>>>(ctx, wo_t, nullptr, out,
                                                input_ids, nullptr, 1024, 8);
}